// Round 7
// baseline (1298.288 us; speedup 1.0000x reference)
//
#include <hip/hip_runtime.h>
#include <math.h>

#define N_SEQ 4096
#define KCH   16
#define DM    256
#define G4    1024
// padded-LDS pitch for the legacy post-round kernels
#define LP    40
#define EP    68   // epilogue scratch pitch in floats
#define GSC   0.0078125f   // 1/(8*16) fp8 scale compensation

typedef __attribute__((ext_vector_type(8))) short bf8;
typedef __attribute__((ext_vector_type(4))) float f4;

__device__ __forceinline__ float fast_rcp(float x) { return __builtin_amdgcn_rcpf(x); }
__device__ __forceinline__ float sigf(float x)   { return fast_rcp(1.f + __expf(-x)); }
__device__ __forceinline__ float tanh_f(float x) { return 1.f - 2.f * fast_rcp(1.f + __expf(2.f * x)); }

__device__ __forceinline__ float bf2f(unsigned short u) {
    return __uint_as_float(((unsigned)u) << 16);
}
__device__ __forceinline__ unsigned short f2bf(float f) {
    unsigned u = __float_as_uint(f);
    unsigned r = (u + 0x7fffu + ((u >> 16) & 1u)) >> 16;   // RNE
    return (unsigned short)r;
}
__device__ __forceinline__ unsigned pack2(float a, float b) {
    return (unsigned)f2bf(a) | ((unsigned)f2bf(b) << 16);
}
// OCP e4m3 helpers (gfx950 v_cvt_pk_fp8_f32 is OCP on this chip)
__device__ __forceinline__ unsigned char f2fp8(float x) {
    return (unsigned char)(__builtin_amdgcn_cvt_pk_fp8_f32(x, 0.f, 0, false) & 0xff);
}
__device__ __forceinline__ unsigned pack4fp8(float a, float b, float c, float d) {
    unsigned p = __builtin_amdgcn_cvt_pk_fp8_f32(a, b, 0, false);
    return __builtin_amdgcn_cvt_pk_fp8_f32(c, d, p, true);
}
__device__ __forceinline__ float fp8dec(unsigned char u) {
    const int e = (u >> 3) & 15, m = u & 7;
    float v = (e == 0) ? (float)m * 0.001953125f
                       : (float)(8 + m) * __uint_as_float((unsigned)(e + 117) << 23);
    return (u & 0x80) ? -v : v;
}

// async global->LDS, 16B per lane; LDS dest = wave-uniform base + lane*16
#define GLDS(gp, lp) __builtin_amdgcn_global_load_lds( \
    (const __attribute__((address_space(1))) void*)(gp), \
    (__attribute__((address_space(3))) void*)(lp), 16, 0, 0)

#define VW(n) asm volatile("s_waitcnt vmcnt(" #n ")" ::: "memory")

// ===========================================================================
// FP8 pipelined MFMA pass: acc[4][4] += A[128,K]@B[128,K]^T, e4m3, over NSEG
// segments of K=256.  Tiles [128][32] fp8 = 4KB each; 5 buffers x 8KB = 40KB
// -> 4 blocks/CU.  2 GLDS/wave/step, lead 4, single barrier per step:
//   step t: vmcnt(6) -> own step-t loads landed (t+1..t+3 stay in flight)
//           s_barrier -> tile complete; buffer (t+4)%5 == (t-1)%5 dead
//           GLDS step t+4 ; ds_read_b64 frags ; 16 MFMA (setprio 1)
// Staging lane map: lane l -> row wave*32+(l>>1), 16B half (l&1); LDS linear
// [128][32] (GLDS dest = wave base + lane*16 lands exactly row-major).
// Frag map (16x16x32 fp8, 8 vals/lane): row = lane&15, k = (lane>>4)*8..+7.
// ===========================================================================
template<int NSEG>
__device__ __forceinline__ void pass_pipe8(
    const unsigned char* const (&segA)[NSEG],
    const unsigned char* const (&segB)[NSEG],
    unsigned char* SM8,
    f4 (&acc)[4][4], int wave, int wm, int wn, int lane)
{
    constexpr int NS = NSEG * 8;
    constexpr int L  = 4;
    constexpr int NP = (NS < L) ? NS : L;
    const int fr = lane & 15, kh = (lane >> 4) * 8;

#pragma unroll
    for (int p = 0; p < NP; ++p) {
        const unsigned char* A_ = segA[p >> 3] + (p & 7) * 32;
        const unsigned char* B_ = segB[p >> 3] + (p & 7) * 32;
        unsigned char* a = SM8 + (p % 5) * 8192 + wave * 1024;
        unsigned char* b = a + 4096;
        GLDS(A_, a);  GLDS(B_, b);
    }
#pragma unroll
    for (int t = 0; t < NS; ++t) {
        const int rem = NS - 1 - t;
        if (rem >= 3)      VW(6);
        else if (rem == 2) VW(4);
        else if (rem == 1) VW(2);
        else               VW(0);
        __builtin_amdgcn_s_barrier();

        if (t + L < NS) {
            const int tn = t + L;
            const unsigned char* A_ = segA[tn >> 3] + (tn & 7) * 32;
            const unsigned char* B_ = segB[tn >> 3] + (tn & 7) * 32;
            unsigned char* a = SM8 + (tn % 5) * 8192 + wave * 1024;
            unsigned char* b = a + 4096;
            GLDS(A_, a);  GLDS(B_, b);
        }

        const unsigned char* Ab = SM8 + (t % 5) * 8192;
        const unsigned char* Bb = Ab + 4096;
        long af[4], bb[4];
#pragma unroll
        for (int i = 0; i < 4; ++i)
            af[i] = *(const long*)(Ab + (wm + i * 16 + fr) * 32 + kh);
#pragma unroll
        for (int j = 0; j < 4; ++j)
            bb[j] = *(const long*)(Bb + (wn + j * 16 + fr) * 32 + kh);

        __builtin_amdgcn_s_setprio(1);
#pragma unroll
        for (int i = 0; i < 4; ++i)
#pragma unroll
            for (int j = 0; j < 4; ++j)
                acc[i][j] = __builtin_amdgcn_mfma_f32_16x16x32_fp8_fp8(
                    af[i], bb[j], acc[i][j], 0, 0, 0);
        __builtin_amdgcn_s_setprio(0);
    }
}

// ===========================================================================
// bf16 2-buffer pipe (32KB LDS) for the in-scan acc role (fits 40KB SMEM).
// Lead 1: wait own step (VW0), barrier, issue t+1, compute.
// ===========================================================================
template<int NSEG, int LDB>
__device__ __forceinline__ void pass_pipe2(
    const unsigned short* const (&segA)[NSEG],
    const unsigned short* const (&segB)[NSEG],
    unsigned short* SM,
    f4 (&acc)[4][4], int wave, int wm, int wn, int jq, int fr)
{
    constexpr int NS = NSEG * 8;
    {
        const unsigned short* A_ = segA[0];
        const unsigned short* B_ = segB[0];
        unsigned short* a = SM + wave * 1024;
        unsigned short* b = a + 4096;
        GLDS(A_, a);        GLDS(A_ + 16 * DM, a + 512);
        GLDS(B_, b);        GLDS(B_ + 16 * LDB, b + 512);
    }
#pragma unroll
    for (int t = 0; t < NS; ++t) {
        VW(0);
        __builtin_amdgcn_s_barrier();
        if (t + 1 < NS) {
            const int tn = t + 1;
            const unsigned short* A_ = segA[tn >> 3] + (tn & 7) * 32;
            const unsigned short* B_ = segB[tn >> 3] + (tn & 7) * 32;
            unsigned short* a = SM + (tn & 1) * 8192 + wave * 1024;
            unsigned short* b = a + 4096;
            GLDS(A_, a);    GLDS(A_ + 16 * DM, a + 512);
            GLDS(B_, b);    GLDS(B_ + 16 * LDB, b + 512);
        }
        const unsigned short* Ab = SM + (t & 1) * 8192;
        const unsigned short* Bb = Ab + 4096;
        bf8 af[4], bb[4];
#pragma unroll
        for (int i = 0; i < 4; ++i)
            af[i] = *(const bf8*)(Ab + (wm + i * 16 + fr) * 32 + jq);
#pragma unroll
        for (int j = 0; j < 4; ++j)
            bb[j] = *(const bf8*)(Bb + (wn + j * 16 + fr) * 32 + jq);
#pragma unroll
        for (int i = 0; i < 4; ++i)
#pragma unroll
            for (int j = 0; j < 4; ++j)
                acc[i][j] = __builtin_amdgcn_mfma_f32_16x16x32_bf16(
                    af[i], bb[j], acc[i][j], 0, 0, 0);
    }
}

// ===========================================================================
// bf16 5-buffer pipe (80KB) — unchanged, used by standalone k_acc_tail.
// ===========================================================================
template<int NSEG, int LDB>
__device__ __forceinline__ void pass_pipe(
    const unsigned short* const (&segA)[NSEG],
    const unsigned short* const (&segB)[NSEG],
    unsigned short* SM,
    f4 (&acc)[4][4], int wave, int wm, int wn, int jq, int fr)
{
    constexpr int NS = NSEG * 8;
    constexpr int L  = 4;
    constexpr int NP = (NS < L) ? NS : L;
#pragma unroll
    for (int p = 0; p < NP; ++p) {
        const unsigned short* A_ = segA[p >> 3] + (p & 7) * 32;
        const unsigned short* B_ = segB[p >> 3] + (p & 7) * 32;
        unsigned short* a = SM + (p % 5) * 8192 + wave * 1024;
        unsigned short* b = a + 4096;
        GLDS(A_, a);        GLDS(A_ + 16 * DM, a + 512);
        GLDS(B_, b);        GLDS(B_ + 16 * LDB, b + 512);
    }
#pragma unroll
    for (int t = 0; t < NS; ++t) {
        const int rem = NS - 1 - t;
        if (rem >= 3)      VW(12);
        else if (rem == 2) VW(8);
        else if (rem == 1) VW(4);
        else               VW(0);
        __builtin_amdgcn_s_barrier();
        if (t + L < NS) {
            const int tn = t + L;
            const unsigned short* A_ = segA[tn >> 3] + (tn & 7) * 32;
            const unsigned short* B_ = segB[tn >> 3] + (tn & 7) * 32;
            unsigned short* a = SM + (tn % 5) * 8192 + wave * 1024;
            unsigned short* b = a + 4096;
            GLDS(A_, a);    GLDS(A_ + 16 * DM, a + 512);
            GLDS(B_, b);    GLDS(B_ + 16 * LDB, b + 512);
        }
        const unsigned short* Ab = SM + (t % 5) * 8192;
        const unsigned short* Bb = Ab + 4096;
        bf8 af[4], bb[4];
#pragma unroll
        for (int i = 0; i < 4; ++i)
            af[i] = *(const bf8*)(Ab + (wm + i * 16 + fr) * 32 + jq);
#pragma unroll
        for (int j = 0; j < 4; ++j)
            bb[j] = *(const bf8*)(Bb + (wn + j * 16 + fr) * 32 + jq);
        __builtin_amdgcn_s_setprio(1);
#pragma unroll
        for (int i = 0; i < 4; ++i)
#pragma unroll
            for (int j = 0; j < 4; ++j)
                acc[i][j] = __builtin_amdgcn_mfma_f32_16x16x32_bf16(
                    af[i], bb[j], acc[i][j], 0, 0, 0);
        __builtin_amdgcn_s_setprio(0);
    }
}

// ===========================================================================
// Legacy padded-LDS passes (post-round one-shot kernels; proven correct)
// ===========================================================================
template<int KLEN>
__device__ __forceinline__ void pass_bf(
    const unsigned short* __restrict__ aRow,
    const unsigned short* __restrict__ bRow,
    unsigned short* Asm, unsigned short* Bsm, f4 (&acc)[4][4])
{
    const int tid  = threadIdx.x;
    const int kh   = (tid & 1) * 16;
    const int srow = tid >> 1;
    const int lane = tid & 63, wave = tid >> 6;
    const int wm = (wave >> 1) * 64, wn = (wave & 1) * 64;
    const int fr = lane & 15, fk = (lane >> 4) * 8;
    unsigned short* da = Asm + srow * LP + kh;
    unsigned short* db = Bsm + srow * LP + kh;

    for (int k0 = 0; k0 < KLEN; k0 += 32) {
        __syncthreads();
        *(int4*)(da)     = *(const int4*)(aRow + k0 + kh);
        *(int4*)(da + 8) = *(const int4*)(aRow + k0 + kh + 8);
        *(int4*)(db)     = *(const int4*)(bRow + k0 + kh);
        *(int4*)(db + 8) = *(const int4*)(bRow + k0 + kh + 8);
        __syncthreads();
        bf8 af[4], bb[4];
#pragma unroll
        for (int i = 0; i < 4; ++i)
            af[i] = *(const bf8*)(Asm + (wm + i * 16 + fr) * LP + fk);
#pragma unroll
        for (int j = 0; j < 4; ++j)
            bb[j] = *(const bf8*)(Bsm + (wn + j * 16 + fr) * LP + fk);
#pragma unroll
        for (int i = 0; i < 4; ++i)
#pragma unroll
            for (int j = 0; j < 4; ++j)
                acc[i][j] = __builtin_amdgcn_mfma_f32_16x16x32_bf16(
                    af[i], bb[j], acc[i][j], 0, 0, 0);
    }
}

template<int KLEN>
__device__ __forceinline__ void pass_f32(
    const float* __restrict__ aRow,
    const unsigned short* __restrict__ bRow,
    unsigned short* Asm, unsigned short* Bsm, f4 (&acc)[4][4])
{
    const int tid  = threadIdx.x;
    const int kh   = (tid & 1) * 16;
    const int srow = tid >> 1;
    const int lane = tid & 63, wave = tid >> 6;
    const int wm = (wave >> 1) * 64, wn = (wave & 1) * 64;
    const int fr = lane & 15, fk = (lane >> 4) * 8;
    unsigned short* da = Asm + srow * LP + kh;
    unsigned short* db = Bsm + srow * LP + kh;

    for (int k0 = 0; k0 < KLEN; k0 += 32) {
        __syncthreads();
        {
            const float* s = aRow + k0 + kh;
            float4 v0 = *(const float4*)(s);
            float4 v1 = *(const float4*)(s + 4);
            float4 v2 = *(const float4*)(s + 8);
            float4 v3 = *(const float4*)(s + 12);
            *(int4*)(da)     = make_int4(pack2(v0.x, v0.y), pack2(v0.z, v0.w),
                                         pack2(v1.x, v1.y), pack2(v1.z, v1.w));
            *(int4*)(da + 8) = make_int4(pack2(v2.x, v2.y), pack2(v2.z, v2.w),
                                         pack2(v3.x, v3.y), pack2(v3.z, v3.w));
        }
        *(int4*)(db)     = *(const int4*)(bRow + k0 + kh);
        *(int4*)(db + 8) = *(const int4*)(bRow + k0 + kh + 8);
        __syncthreads();
        bf8 af[4], bb[4];
#pragma unroll
        for (int i = 0; i < 4; ++i)
            af[i] = *(const bf8*)(Asm + (wm + i * 16 + fr) * LP + fk);
#pragma unroll
        for (int j = 0; j < 4; ++j)
            bb[j] = *(const bf8*)(Bsm + (wn + j * 16 + fr) * LP + fk);
#pragma unroll
        for (int i = 0; i < 4; ++i)
#pragma unroll
            for (int j = 0; j < 4; ++j)
                acc[i][j] = __builtin_amdgcn_mfma_f32_16x16x32_bf16(
                    af[i], bb[j], acc[i][j], 0, 0, 0);
    }
}

// --------------------------- setup kernels ----------------------------------

__global__ __launch_bounds__(256) void k_lastidx(
    const int* __restrict__ indice, int* __restrict__ last_idx)
{
    const int n = blockIdx.x * 256 + threadIdx.x;
    if (n >= N_SEQ) return;
    int len = 0;
#pragma unroll
    for (int k = 0; k < KCH; ++k) len += (indice[n * KCH + k] != -1);
    last_idx[n] = indice[n * KCH + (len - 1)];
}

__global__ __launch_bounds__(1024) void k_hh0_bsum2(
    const float* __restrict__ bih, const float* __restrict__ bhh,
    const float* __restrict__ h0, const float* __restrict__ Whh,
    float* __restrict__ bsum2)
{
    const int jz = blockIdx.x, j = jz + 1;
    const int g = threadIdx.x;
    const int jd = j * 2 + 1;
    const float* wrow = Whh + ((size_t)jd * G4 + g) * DM;
    float s = bih[jd * G4 + g] + bhh[jd * G4 + g];
    for (int h = 0; h < DM; ++h) s = fmaf(h0[j * DM + h], wrow[h], s);
    const int c = (g & 255) * 4 + (g >> 8);
    bsum2[jz * G4 + c] = s;
}

__global__ __launch_bounds__(256) void k_init_states(
    const float* __restrict__ h0, const float* __restrict__ c0,
    unsigned char* __restrict__ hA8, float* __restrict__ c_state)
{
    const int row = blockIdx.x;
    const int s = row >> 12;
    const int tree = (s < 4) ? s : 0;
    const int d = threadIdx.x;
    hA8[(size_t)row * DM + d]     = f2fp8(h0[tree * DM + d] * 8.f);
    c_state[(size_t)row * DM + d] = c0[tree * DM + d];
}

__global__ __launch_bounds__(256) void k_zero4(float4* __restrict__ p)
{
    p[(size_t)blockIdx.x * 256 + threadIdx.x] = make_float4(0.f, 0.f, 0.f, 0.f);
}

// wcat8: fp8 weights, scaled x16.  row = [x-half 256B | h-half 256B]
__global__ __launch_bounds__(256) void k_prep_wcat(
    const float* __restrict__ Wih, const float* __restrict__ Whh,
    const float* __restrict__ bih, const float* __restrict__ bhh,
    unsigned char* __restrict__ wcat8, float* __restrict__ bsumr)
{
    const int c = blockIdx.x, s = blockIdx.y;
    const int wsel = (s < 4) ? s * 2 : 1;
    const int d = c >> 2, g = c & 3;
    const size_t srcrow = ((size_t)wsel * G4 + g * DM + d) * DM;
    unsigned char* dst = wcat8 + ((size_t)s * G4 + c) * 512;
    const int t = threadIdx.x;
    dst[t]       = f2fp8(Wih[srcrow + t] * 16.f);
    dst[256 + t] = f2fp8(Whh[srcrow + t] * 16.f);
    if (t == 0)
        bsumr[s * G4 + c] = bih[wsel * G4 + g * DM + d] + bhh[wsel * G4 + g * DM + d];
}

__global__ __launch_bounds__(256) void k_prep_wcat2(
    const float* __restrict__ Wih, unsigned short* __restrict__ wcat2)
{
    const int c = blockIdx.x, jz = blockIdx.y, j = jz + 1;
    const int d = c >> 2, g = c & 3;
    const size_t srcrow = ((size_t)(j * 2 + 1) * G4 + g * DM + d) * DM;
    wcat2[((size_t)jz * G4 + c) * 256 + threadIdx.x] = f2bf(Wih[srcrow + threadIdx.x]);
}

__global__ __launch_bounds__(256) void k_prep_fcb(
    const float* __restrict__ fc, unsigned short* __restrict__ fcb)
{
    const int dout = blockIdx.x, z = blockIdx.y, t = threadIdx.x;
    fcb[((size_t)z * DM + dout) * DM + t] = f2bf(fc[(size_t)dout * 512 + z * DM + t]);
}

__global__ __launch_bounds__(256) void k_prep_fcb2(
    const float* __restrict__ fc, unsigned short* __restrict__ fcb2)
{
    const int dout = blockIdx.x, jz = blockIdx.y, j = jz + 1, t = threadIdx.x;
    const float* src = fc + ((size_t)j * DM + dout) * 512;
    unsigned short* dst = fcb2 + ((size_t)jz * DM + dout) * 512;
    dst[t]       = f2bf(src[t]);
    dst[t + 256] = f2bf(src[t + 256]);
}

__global__ __launch_bounds__(256) void k_prep_wwb(
    const float* __restrict__ W_w, unsigned short* __restrict__ wwb)
{
    const size_t i = (size_t)blockIdx.x * 256 + threadIdx.x;
    wwb[i] = f2bf(W_w[i]);
}

// gather child hidden states as fp8 (scale x8)
__device__ __forceinline__ void gather_slice8(
    const float* __restrict__ h_tensor, const int* __restrict__ indice,
    unsigned char* __restrict__ xbuf, int zz, int kk, int blk)
{
    const int row = blk * 64 + (threadIdx.x >> 2);
    const int cb  = (threadIdx.x & 3) * 64;
    int idx = indice[row * KCH + kk]; if (idx < 0) idx = 0;
    const float* src = h_tensor + (size_t)idx * DM + cb;
    unsigned char* dst = xbuf + ((size_t)zz * N_SEQ + row) * DM + cb;
#pragma unroll
    for (int c = 0; c < 64; c += 16) {
        unsigned q[4];
#pragma unroll
        for (int u = 0; u < 4; ++u) {
            float4 v = *(const float4*)(src + c + u * 4);
            q[u] = pack4fp8(v.x * 8.f, v.y * 8.f, v.z * 8.f, v.w * 8.f);
        }
        *(uint4*)(dst + c) = make_uint4(q[0], q[1], q[2], q[3]);
    }
}

__global__ __launch_bounds__(256) void k_gather_x0(
    const float* __restrict__ h_tensor, const int* __restrict__ indice,
    unsigned char* __restrict__ xbuf)
{
    const int slice = blockIdx.x >> 6, blk = blockIdx.x & 63;
    gather_slice8(h_tensor, indice, xbuf, slice, slice ? (KCH - 1) : 0, blk);
}

// --------------------------- merged scan round ------------------------------
// grid (8, 32, 6):
//   bz<5 : fp8 scan for stream s=bz (XCD-swizzled as before)
//   bz=5 : id5<128 -> bf16 acc_fc round r-1 (2-buf pipe);
//          id5>=128 -> fp8 gather for round r+1
__global__ __launch_bounds__(256) void k_scan_merged(
    const unsigned char* __restrict__ xb_cur, unsigned char* __restrict__ xb_nxt,
    const unsigned short* __restrict__ yb_prev, unsigned short* __restrict__ yb_cur,
    const int* __restrict__ indice, const float* __restrict__ h_tensor,
    const unsigned char* __restrict__ h_in, unsigned char* __restrict__ h_out,
    float* __restrict__ c_state,
    const unsigned char* __restrict__ wcat8, const float* __restrict__ bsumr,
    const unsigned short* __restrict__ fcb, unsigned short* __restrict__ ys0,
    unsigned short* __restrict__ hfin, int r)
{
    __shared__ __align__(16) unsigned char SMEM8[40960];   // 5 fp8 bufs / 2 bf16 bufs

    const int tid  = threadIdx.x;
    const int lane = tid & 63, wave = tid >> 6;
    const int wm = (wave >> 1) * 64, wn = (wave & 1) * 64;
    const int fr = lane & 15;

    const int bz = blockIdx.z;

    if (bz == 5) {
        const int id5 = blockIdx.x + 8 * blockIdx.y;
        if (id5 >= 128) {                 // gather role: fp8 xbuf for round r+1
            const int rr = r + 1;
            if (rr >= KCH) return;
            const int g = id5 - 128;
            const int zz = g >> 6;
            gather_slice8(h_tensor, indice, xb_nxt, zz,
                          zz ? (KCH - 1 - rr) : rr, g & 63);
            return;
        }
        if (r == 0) return;               // acc role: bf16 fc-accumulate r-1
        const int jq = ((lane >> 4) ^ ((fr >> 1) & 3)) * 8;
        const int lr = wave * 32 + (lane >> 2);
        const int jl = ((lane & 3) ^ ((lane >> 3) & 3)) * 8;
        unsigned short* SMS = (unsigned short*)SMEM8;
        const int rp = r - 1;
        const int z = id5 >> 6;
        const int kslice = z ? (KCH - 1 - rp) : rp;
        const int row0 = (id5 & 31) * 128;
        const int c0 = ((id5 >> 5) & 1) * 128;

        const unsigned short* ay0 = yb_prev + ((size_t)z * N_SEQ + row0 + lr) * DM + jl;
        const unsigned short* bf0 = fcb + ((size_t)z * DM + c0 + lr) * DM + jl;

        f4 acc[4][4];
#pragma unroll
        for (int i = 0; i < 4; ++i)
#pragma unroll
            for (int j = 0; j < 4; ++j) acc[i][j] = (f4)(0.f);
        {
            const unsigned short* const segA[1] = { ay0 };
            const unsigned short* const segB[1] = { bf0 };
            pass_pipe2<1, 256>(segA, segB, SMS, acc, wave, wm, wn, jq, fr);
        }
#pragma unroll
        for (int i = 0; i < 4; ++i)
#pragma unroll
            for (int j = 0; j < 4; ++j) {
                const int col = c0 + wn + j * 16 + fr;
#pragma unroll
                for (int reg = 0; reg < 4; ++reg) {
                    const int rowg = row0 + wm + i * 16 + (lane >> 4) * 4 + reg;
                    const size_t ix = ((size_t)rowg * KCH + kslice) * DM + col;
                    ys0[ix] = f2bf(bf2f(ys0[ix]) + acc[i][j][reg]);
                }
            }
        return;
    }

    // ---- fp8 scan role ----
    const int s = bz;
    const int k = (s < 4) ? r : (KCH - 1 - r);
    const int z = (s < 4) ? 0 : 1;
    const int bn = blockIdx.y & 7;
    const int bm = (blockIdx.y >> 3) * 8 + blockIdx.x;
    const int row0 = bm * 128, c0 = bn * 128;

    const int lr8 = wave * 32 + (lane >> 1);
    const int ch8 = (lane & 1) * 16;
    const unsigned char* xz = xb_cur + (size_t)z * N_SEQ * DM;
    const unsigned char* hs_in = h_in + (size_t)s * N_SEQ * DM;
    const unsigned char* ax0 = xz + (size_t)(row0 + lr8) * DM + ch8;
    const unsigned char* ah0 = hs_in + (size_t)(row0 + lr8) * DM + ch8;
    const unsigned char* bw0 = wcat8 + ((size_t)s * G4 + c0 + lr8) * 512 + ch8;

    f4 acc[4][4];
#pragma unroll
    for (int i = 0; i < 4; ++i)
#pragma unroll
        for (int j = 0; j < 4; ++j) acc[i][j] = (f4)(0.f);

    {
        const unsigned char* const segA[2] = { ax0, ah0 };
        const unsigned char* const segB[2] = { bw0, bw0 + 256 };
        pass_pipe8<2>(segA, segB, SMEM8, acc, wave, wm, wn, lane);
    }

    // ---- fused LSTM epilogue (coalesced, masked-skip), acc scaled by 1/128 ----
    float* sc = (float*)SMEM8 + wave * (16 * EP);
    __syncthreads();   // SMEM handoff from MFMA tiles (cross-wave)
    const int kprev = (s < 4) ? (k - 1) : (k + 1);
    const int dq = lane & 15;
    const int rq = lane >> 4;
    const bool fin = (r == KCH - 1) && (s >= 1) && (s < 4);
#pragma unroll
    for (int i = 0; i < 4; ++i) {
#pragma unroll
        for (int j = 0; j < 4; ++j) {
            const int colL = j * 16 + fr;
            const int rbase = (lane >> 4) * 4;
#pragma unroll
            for (int reg = 0; reg < 4; ++reg)
                sc[(rbase + reg) * EP + colL] = acc[i][j][reg];
        }
        asm volatile("s_waitcnt lgkmcnt(0)" ::: "memory");
        __builtin_amdgcn_sched_barrier(0);
#pragma unroll
        for (int q = 0; q < 4; ++q) {
            const int rloc = rq + q * 4;
            const int rowg = row0 + wm + i * 16 + rloc;
            const bool m = (indice[rowg * KCH + k] != -1);
            const bool mpv = (r == 0) ? true : (indice[rowg * KCH + kprev] != -1);
            const f4 gv = *(const f4*)(sc + rloc * EP + dq * 4);
            const f4 bb = *(const f4*)(bsumr + s * G4 + c0 + wn + dq * 4);
            const int d = ((c0 + wn) >> 2) + dq;
            const size_t cix = ((size_t)s * N_SEQ + rowg) * DM + d;
            unsigned short yv = 0;
            if (m) {
                const float ii = sigf(gv.x * GSC + bb.x);
                const float ff = sigf(gv.y * GSC + bb.y);
                const float uu = tanh_f(gv.z * GSC + bb.z);
                const float oo = sigf(gv.w * GSC + bb.w);
                const float c_old = c_state[cix];
                const float cn = ff * c_old + ii * uu;
                c_state[cix] = cn;
                const float hn = oo * tanh_f(cn);
                h_out[cix] = f2fp8(hn * 8.f);
                yv = f2bf(hn);
                if (fin)
                    hfin[((size_t)(s - 1) * N_SEQ + rowg) * DM + d] = yv;
            } else if (mpv || fin) {
                const unsigned char hb = hs_in[(size_t)rowg * DM + d];
                if (mpv) h_out[cix] = hb;
                if (fin)
                    hfin[((size_t)(s - 1) * N_SEQ + rowg) * DM + d] =
                        f2bf(fp8dec(hb) * 0.125f);
            }
            if (s == 0)
                yb_cur[(size_t)rowg * DM + d] = m ? yv : (unsigned short)0;
            else if (s == 4)
                yb_cur[(size_t)(N_SEQ + rowg) * DM + d] = m ? yv : (unsigned short)0;
        }
        asm volatile("s_waitcnt lgkmcnt(0)" ::: "memory");
        __builtin_amdgcn_sched_barrier(0);
    }
}

// tail: acc_fc for r=15.  grid (2, 32, 2) — bf16 5-buf pipe (own 80KB SMEM)
__global__ __launch_bounds__(256) void k_acc_tail(
    const unsigned short* __restrict__ ybuf, const unsigned short* __restrict__ fcb,
    unsigned short* __restrict__ ys0)
{
    __shared__ __align__(16) unsigned short SMEM[40960];
    const int tid = threadIdx.x;
    const int lane = tid & 63, wave = tid >> 6;
    const int wm = (wave >> 1) * 64, wn = (wave & 1) * 64;
    const int fr = lane & 15;
    const int jq = ((lane >> 4) ^ ((fr >> 1) & 3)) * 8;
    const int lr = wave * 32 + (lane >> 2);
    const int jl = ((lane & 3) ^ ((lane >> 3) & 3)) * 8;

    const int z = blockIdx.z;
    const int kslice = z ? 0 : (KCH - 1);
    const int row0 = blockIdx.y * 128, c0 = blockIdx.x * 128;

    const unsigned short* ay0 = ybuf + ((size_t)z * N_SEQ + row0 + lr) * DM + jl;
    const unsigned short* bf0 = fcb + ((size_t)z * DM + c0 + lr) * DM + jl;

    f4 acc[4][4];
#pragma unroll
    for (int i = 0; i < 4; ++i)
#pragma unroll
        for (int j = 0; j < 4; ++j) acc[i][j] = (f4)(0.f);
    {
        const unsigned short* const segA[1] = { ay0 };
        const unsigned short* const segB[1] = { bf0 };
        pass_pipe<1, 256>(segA, segB, SMEM, acc, wave, wm, wn, jq, fr);
    }
#pragma unroll
    for (int i = 0; i < 4; ++i)
#pragma unroll
        for (int j = 0; j < 4; ++j) {
            const int col = c0 + wn + j * 16 + fr;
#pragma unroll
            for (int reg = 0; reg < 4; ++reg) {
                const int rowg = row0 + wm + i * 16 + (lane >> 4) * 4 + reg;
                const size_t ix = ((size_t)rowg * KCH + kslice) * DM + col;
                ys0[ix] = f2bf(bf2f(ys0[ix]) + acc[i][j][reg]);
            }
        }
}

// --------------------------- post-round kernels -----------------------------

__global__ __launch_bounds__(256) void k_bwd_mfma(
    const float* __restrict__ h_tensor, const int* __restrict__ last_idx,
    const unsigned short* __restrict__ wcat2, const float* __restrict__ bsum2,
    const float* __restrict__ c0, unsigned short* __restrict__ yb_last)
{
    __shared__ __align__(16) unsigned short SMEM[2 * 128 * LP];
    const int jz = blockIdx.z, j = jz + 1;
    const int row0 = blockIdx.y * 128, c0t = blockIdx.x * 128;
    const int tid = threadIdx.x;
    const int srow = tid >> 1;

    const float* aF = h_tensor + (size_t)last_idx[row0 + srow] * DM;
    const unsigned short* bR = wcat2 + ((size_t)jz * G4 + c0t + srow) * 256;

    f4 acc[4][4];
#pragma unroll
    for (int i = 0; i < 4; ++i)
#pragma unroll
        for (int jj = 0; jj < 4; ++jj) acc[i][jj] = (f4)(0.f);

    pass_f32<256>(aF, bR, SMEM, SMEM + 128 * LP, acc);

    const int lane = tid & 63, wave = tid >> 6;
    const int wm = (wave >> 1) * 64, wn = (wave & 1) * 64;
    float* sc = (float*)SMEM + wave * (16 * EP);

    __syncthreads();
#pragma unroll
    for (int i = 0; i < 4; ++i) {
#pragma unroll
        for (int jj = 0; jj < 4; ++jj) {
            const int colL = jj * 16 + (lane & 15);
            const int rbase = (lane >> 4) * 4;
#pragma unroll
            for (int reg = 0; reg < 4; ++reg)
                sc[(rbase + reg) * EP + colL] = acc[i][jj][reg];
        }
        __syncthreads();
        const int rowg = row0 + wm + i * 16 + (lane & 15);
#pragma unroll
        for (int q = 0; q < 4; ++q) {
            const int dL = (lane >> 4) + q * 4;
            const f4 gv = *(const f4*)(sc + (lane & 15) * EP + dL * 4);
            const f4 bb = *(const f4*)(bsum2 + jz * G4 + c0t + wn + dL * 4);
            const int d = ((c0t + wn) >> 2) + dL;
            const float ii = sigf(gv.x + bb.x);
            const float ff = sigf(gv.y + bb.y);
            const float uu = tanh_f(gv.z + bb.z);
            const float oo = sigf(gv.w + bb.w);
            const float cn = ff * c0[j * DM + d] + ii * uu;
            yb_last[((size_t)jz * N_SEQ + rowg) * DM + d] = f2bf(oo * tanh_f(cn));
        }
        __syncthreads();
    }
}

__global__ __launch_bounds__(256) void k_wx_mfma(
    const float* __restrict__ x, const unsigned short* __restrict__ wwb,
    const float* __restrict__ W_b, unsigned short* __restrict__ Wx)
{
    __shared__ __align__(16) unsigned short SMEM[2 * 128 * LP];
    const int row0 = blockIdx.y * 128, c0 = blockIdx.x * 128;
    const int tid = threadIdx.x;
    const int srow = tid >> 1;

    const float* aF = x + (size_t)(row0 + srow) * DM;
    const unsigned short* bR = wwb + (size_t)(c0 + srow) * DM;

    f4 acc[4][4];
#pragma unroll
    for (int i = 0; i < 4; ++i)
#pragma unroll
        for (int j = 0; j < 4; ++j) acc[i][j] = (f4)(0.f);

    pass_f32<256>(aF, bR, SMEM, SMEM + 128 * LP, acc);

    const int lane = tid & 63, wave = tid >> 6;
    const int wm = (wave >> 1) * 64, wn = (wave & 1) * 64;
#pragma unroll
    for (int i = 0; i < 4; ++i)
#pragma unroll
        for (int j = 0; j < 4; ++j) {
            const int col = c0 + wn + j * 16 + (lane & 15);
            const float bv = W_b[col];
#pragma unroll
            for (int reg = 0; reg < 4; ++reg) {
                const int rowg = row0 + wm + i * 16 + (lane >> 4) * 4 + reg;
                Wx[(size_t)rowg * G4 + col] = f2bf(acc[i][j][reg] + bv);
            }
        }
}

__global__ __launch_bounds__(256) void k_fc_last_mfma(
    const unsigned short* __restrict__ hfin, const unsigned short* __restrict__ yb_last,
    const unsigned short* __restrict__ fcb2, unsigned short* __restrict__ ys_last)
{
    __shared__ __align__(16) unsigned short SMEM[2 * 128 * LP];
    const int jz = blockIdx.z;
    const int row0 = blockIdx.y * 128, c0 = blockIdx.x * 128;
    const int tid = threadIdx.x;
    const int srow = tid >> 1;

    const unsigned short* aH1 = hfin + ((size_t)jz * N_SEQ + row0 + srow) * DM;
    const unsigned short* aH2 = yb_last + ((size_t)jz * N_SEQ + row0 + srow) * DM;
    const unsigned short* bR  = fcb2 + ((size_t)jz * DM + c0 + srow) * 512;

    f4 acc[4][4];
#pragma unroll
    for (int i = 0; i < 4; ++i)
#pragma unroll
        for (int j = 0; j < 4; ++j) acc[i][j] = (f4)(0.f);

    pass_bf<256>(aH1, bR, SMEM, SMEM + 128 * LP, acc);
    pass_bf<256>(aH2, bR + 256, SMEM, SMEM + 128 * LP, acc);

    const int lane = tid & 63, wave = tid >> 6;
    const int wm = (wave >> 1) * 64, wn = (wave & 1) * 64;
#pragma unroll
    for (int i = 0; i < 4; ++i)
#pragma unroll
        for (int j = 0; j < 4; ++j) {
            const int col = c0 + wn + j * 16 + (lane & 15);
#pragma unroll
            for (int reg = 0; reg < 4; ++reg) {
                const int rowg = row0 + wm + i * 16 + (lane >> 4) * 4 + reg;
                ys_last[((size_t)jz * N_SEQ + rowg) * DM + col] = f2bf(acc[i][j][reg]);
            }
        }
}

__global__ __launch_bounds__(256) void k_final(
    const unsigned short* __restrict__ Wx, const unsigned short* __restrict__ ys0,
    const unsigned short* __restrict__ ys_last, const float* __restrict__ c_tensor,
    const int* __restrict__ indice, float* __restrict__ out)
{
    const int n = blockIdx.x, d = threadIdx.x;
    const float Wf = bf2f(Wx[(size_t)n * G4 + d]);
    const float Wi = bf2f(Wx[(size_t)n * G4 + DM + d]);
    const float Wu = bf2f(Wx[(size_t)n * G4 + 2 * DM + d]);
    const float Wo = bf2f(Wx[(size_t)n * G4 + 3 * DM + d]);
    float bf = 0.f;
#pragma unroll
    for (int k = 0; k < KCH; ++k) {
        const int id = indice[n * KCH + k];
        if (id >= 0)
            bf += sigf(Wf + bf2f(ys0[((size_t)n * KCH + k) * DM + d])) *
                  c_tensor[(size_t)id * DM + d];
    }
    const float bi = sigf(bf2f(ys_last[((size_t)0 * N_SEQ + n) * DM + d]) + Wi);
    const float bu = tanh_f(bf2f(ys_last[((size_t)1 * N_SEQ + n) * DM + d]) + Wu);
    const float bo = sigf(bf2f(ys_last[((size_t)2 * N_SEQ + n) * DM + d]) + Wo);
    const float nc = bi * bu + bf;
    const float nh = bo * tanh_f(nc);
    out[(size_t)n * DM + d] = nh;
    out[(size_t)N_SEQ * DM + (size_t)n * DM + d] = nc;
}

// --------------------------- launcher ---------------------------------------
extern "C" void kernel_launch(void* const* d_in, const int* in_sizes, int n_in,
                              void* d_out, int out_size, void* d_ws, size_t ws_size,
                              hipStream_t stream)
{
    const float* x        = (const float*)d_in[0];
    const float* h_tensor = (const float*)d_in[1];
    const float* c_tensor = (const float*)d_in[2];
    const int*   indice   = (const int*)d_in[3];
    const float* W_w      = (const float*)d_in[4];
    const float* W_b      = (const float*)d_in[5];
    const float* h0       = (const float*)d_in[6];
    const float* c0       = (const float*)d_in[7];
    const float* Wih      = (const float*)d_in[8];
    const float* Whh      = (const float*)d_in[9];
    const float* bih      = (const float*)d_in[10];
    const float* bhh      = (const float*)d_in[11];
    const float* fc       = (const float*)d_in[12];
    float* out = (float*)d_out;

    // ---- workspace layout (fp8 era); need = 97,816,576 B (proven cap) ----
    char* base = (char*)d_ws;
    float*          c_state  = (float*)(base + 0);                   // 20,971,520
    int*            last_idx = (int*)  (base + 20971520);            //     16,384
    float*          bsumr    = (float*)(base + 20987904);            //     20,480
    unsigned char*  hA8      = (unsigned char*)(base + 21008384);    //  5,242,880
    unsigned char*  hB8      = (unsigned char*)(base + 26251264);    //  5,242,880
    unsigned short* hfin     = (unsigned short*)(base + 31494144);   //  6,291,456
    unsigned short* ys0      = (unsigned short*)(base + 41979904);   // 33,554,432
    unsigned short* ybufA    = (unsigned short*)(base + 75534336);   //  4,194,304
    unsigned short* ybufB    = (unsigned short*)(base + 79728640);   //  4,194,304
    unsigned char*  xbufA8   = (unsigned char*)(base + 83922944);    //  2,097,152
    unsigned char*  xbufB8   = (unsigned char*)(base + 86020096);    //  2,097,152
    unsigned short* fcb      = (unsigned short*)(base + 88117248);   //    262,144
    unsigned short* postbuf  = (unsigned short*)(base + 88379392);   //  4,194,304
    unsigned char*  wcat8    = (unsigned char*)(base + 92573696);    //  2,621,440
    const size_t need = 97816576;
    if (ws_size < need) return;   // diagnostic: zero-output absmax fail

    // post-phase aliases (disjoint lifetimes):
    unsigned short* wcat2   = postbuf;                      // 1,572,864 B
    unsigned short* fcb2    = postbuf + 786432;             //   786,432 B
    unsigned short* wwb     = postbuf + 1179648;            //   524,288 B
    float*          bsum2   = (float*)(postbuf + 1441792);  //    12,288 B
    unsigned short* yb_last = ybufA;                        // spans ybufA+B (6.29MB)
    unsigned short* ys_last = (unsigned short*)(base + 21008384);  // hA8/hB8 dead (6.29MB)
    unsigned short* WxBuf   = (unsigned short*)(base + 27299840);  // 8.39MB; overlaps hfin,
                                                                   // written after fc_last

    k_lastidx<<<16, 256, 0, stream>>>(indice, last_idx);
    k_init_states<<<5 * N_SEQ, 256, 0, stream>>>(h0, c0, hA8, c_state);
    k_zero4<<<8192, 256, 0, stream>>>((float4*)ys0);
    k_prep_wcat<<<dim3(G4, 5), 256, 0, stream>>>(Wih, Whh, bih, bhh, wcat8, bsumr);
    k_prep_fcb<<<dim3(DM, 2), 256, 0, stream>>>(fc, fcb);
    k_gather_x0<<<128, 256, 0, stream>>>(h_tensor, indice, xbufA8);

    for (int r = 0; r < KCH; ++r) {
        const unsigned char* xb_cur = (r & 1) ? xbufB8 : xbufA8;
        unsigned char* xb_nxt       = (r & 1) ? xbufA8 : xbufB8;
        const unsigned short* yb_prev = (r & 1) ? ybufA : ybufB;
        unsigned short* yb_cur        = (r & 1) ? ybufB : ybufA;
        const unsigned char* h_in = (r & 1) ? hB8 : hA8;
        unsigned char* h_out      = (r & 1) ? hA8 : hB8;
        k_scan_merged<<<dim3(8, 32, 6), 256, 0, stream>>>(
            xb_cur, xb_nxt, yb_prev, yb_cur, indice, h_tensor,
            h_in, h_out, c_state, wcat8, bsumr, fcb, ys0, hfin, r);
    }
    // r=15 odd -> y_cur(r=15) in ybufB; final h (bf16, streams 1-3) in hfin.

    k_acc_tail<<<dim3(2, 32, 2), 256, 0, stream>>>(ybufB, fcb, ys0);

    // post preps into postbuf
    k_prep_wcat2<<<dim3(G4, 3), 256, 0, stream>>>(Wih, wcat2);
    k_hh0_bsum2<<<3, 1024, 0, stream>>>(bih, bhh, h0, Whh, bsum2);
    k_prep_fcb2<<<dim3(DM, 3), 256, 0, stream>>>(fc, fcb2);
    k_prep_wwb<<<1024, 256, 0, stream>>>(W_w, wwb);

    k_bwd_mfma<<<dim3(8, 32, 3), 256, 0, stream>>>(
        h_tensor, last_idx, wcat2, bsum2, c0, yb_last);
    k_fc_last_mfma<<<dim3(2, 32, 3), 256, 0, stream>>>(hfin, yb_last, fcb2, ys_last);
    k_wx_mfma<<<dim3(8, 32), 256, 0, stream>>>(x, wwb, W_b, WxBuf);

    k_final<<<N_SEQ, 256, 0, stream>>>(WxBuf, ys0, ys_last, c_tensor, indice, out);
}